// Round 2
// baseline (263.448 us; speedup 1.0000x reference)
//
#include <hip/hip_runtime.h>

namespace {
constexpr int NB = 131072;
constexpr int NJ = 24;
constexpr int PAR[NJ] = {0,0,0,0,1,2,3,4,5,6,7,8,9,9,9,12,13,14,16,17,18,19,20,21};
}

__global__ __launch_bounds__(256) void pose_kernel(
    const float* __restrict__ rot,
    const float* __restrict__ pos,
    float* __restrict__ outT,
    float* __restrict__ outP)
{
    int b = blockIdx.x * 256 + threadIdx.x;
    if (b >= NB) return;
    const float* r = rot + (size_t)b * (NJ * 9);
    const float* p = pos + (size_t)b * (NJ * 3);
    float* oT = outT + (size_t)b * (NJ * 16);
    float* oP = outP + (size_t)b * (NJ * 3);

    // ---- load all 24 positions (72 floats) via aligned float4 ----
    float P[NJ * 3];
    #pragma unroll
    for (int i = 0; i < (NJ * 3) / 4; ++i) {
        float4 v = reinterpret_cast<const float4*>(p)[i];
        P[4*i+0] = v.x; P[4*i+1] = v.y; P[4*i+2] = v.z; P[4*i+3] = v.w;
    }

    // global transforms per joint: rotation (row-major 3x3) + translation.
    // All indexing below is compile-time constant after full unroll, so these
    // live in registers with tree-structured live ranges (~5 live at peak).
    float Rg[NJ][9];
    float tg[NJ][3];

    #pragma unroll
    for (int j = 0; j < NJ; ++j) {
        const int pj = PAR[j];

        // local rotation: 9 contiguous floats (compiler merges loads)
        float L[9];
        #pragma unroll
        for (int k = 0; k < 9; ++k) L[k] = r[9*j + k];

        // parent-relative translation
        float rel[3];
        if (j == 0) {
            rel[0] = P[0]; rel[1] = P[1]; rel[2] = P[2];
        } else {
            rel[0] = P[3*j+0] - P[3*pj+0];
            rel[1] = P[3*j+1] - P[3*pj+1];
            rel[2] = P[3*j+2] - P[3*pj+2];
        }

        if (j == 0) {
            #pragma unroll
            for (int k = 0; k < 9; ++k) Rg[0][k] = L[k];
            tg[0][0] = rel[0]; tg[0][1] = rel[1]; tg[0][2] = rel[2];
        } else {
            #pragma unroll
            for (int row = 0; row < 3; ++row) {
                #pragma unroll
                for (int col = 0; col < 3; ++col) {
                    Rg[j][3*row+col] = Rg[pj][3*row+0] * L[0*3+col]
                                     + Rg[pj][3*row+1] * L[1*3+col]
                                     + Rg[pj][3*row+2] * L[2*3+col];
                }
                tg[j][row] = Rg[pj][3*row+0] * rel[0]
                           + Rg[pj][3*row+1] * rel[1]
                           + Rg[pj][3*row+2] * rel[2]
                           + tg[pj][row];
            }
        }

        // init_bone = Rg[j] @ rest_pos ; output rows as float4
        float px = P[3*j+0], py = P[3*j+1], pz = P[3*j+2];
        #pragma unroll
        for (int row = 0; row < 3; ++row) {
            float ib = Rg[j][3*row+0]*px + Rg[j][3*row+1]*py + Rg[j][3*row+2]*pz;
            float4 o = make_float4(Rg[j][3*row+0], Rg[j][3*row+1], Rg[j][3*row+2],
                                   tg[j][row] - ib);
            *reinterpret_cast<float4*>(oT + 16*j + 4*row) = o;
        }
        *reinterpret_cast<float4*>(oT + 16*j + 12) = make_float4(0.f, 0.f, 0.f, 1.f);

        oP[3*j+0] = tg[j][0];
        oP[3*j+1] = tg[j][1];
        oP[3*j+2] = tg[j][2];
    }
}

extern "C" void kernel_launch(void* const* d_in, const int* in_sizes, int n_in,
                              void* d_out, int out_size, void* d_ws, size_t ws_size,
                              hipStream_t stream) {
    const float* rot = (const float*)d_in[0];
    const float* pos = (const float*)d_in[1];
    float* outT = (float*)d_out;
    float* outP = outT + (size_t)NB * NJ * 16;
    dim3 grid(NB / 256), block(256);
    hipLaunchKernelGGL(pose_kernel, grid, block, 0, stream, rot, pos, outT, outP);
}

// Round 5
// 135.331 us; speedup vs baseline: 1.9467x; 1.9467x over previous
//
#include <hip/hip_runtime.h>

namespace {
constexpr int NB  = 131072;
constexpr int NJ  = 24;
constexpr int PAR[NJ] = {0,0,0,0,1,2,3,4,5,6,7,8,9,9,9,12,13,14,16,17,18,19,20,21};
constexpr int BLK = 256;        // threads = batches per block
constexpr int SPR = 76;         // LDS row stride (floats) for pos/rot staging (72 data + 4 pad)
constexpr int SOT = 68;         // LDS row stride for oT staging (64 data + 4 pad)
constexpr int SOP = 28;         // LDS row stride for oP staging (24 data + 4 pad)
constexpr int LDSF = BLK * SPR; // 19456 floats = 77824 B -> 2 blocks/CU
}

__global__ __launch_bounds__(BLK, 2) void pose_kernel(
    const float* __restrict__ rot,
    const float* __restrict__ pos,
    float* __restrict__ outT,
    float* __restrict__ outP)
{
    __shared__ __align__(16) float lds[LDSF];
    const int t  = threadIdx.x;
    const int b0 = blockIdx.x * BLK;

    // ---- Phase 1: stage positions (256 rows x 72 floats) coalesced -> LDS ----
    {
        const float* g = pos + (size_t)b0 * 72;
        #pragma unroll
        for (int i = 0; i < 18; ++i) {
            int f = t + BLK * i;           // float4 index, 4608 total
            int row = f / 18, col = f % 18;
            float4 v = *reinterpret_cast<const float4*>(g + (size_t)row * 72 + col * 4);
            *reinterpret_cast<float4*>(&lds[row * SPR + col * 4]) = v;
        }
    }
    __syncthreads();
    float P[72];
    #pragma unroll
    for (int i = 0; i < 72; ++i) P[i] = lds[t * SPR + i];

    float Rg[NJ][9];
    float tg[NJ][3];

    #pragma unroll
    for (int gidx = 0; gidx < 3; ++gidx) {
        __syncthreads();  // all lanes done reading previous LDS contents

        // ---- stage rot for joints 8g..8g+7 (72 floats/batch) coalesced -> LDS ----
        {
            const float* g = rot + (size_t)b0 * 216 + gidx * 72;
            #pragma unroll
            for (int i = 0; i < 18; ++i) {
                int f = t + BLK * i;
                int row = f / 18, col = f % 18;
                float4 v = *reinterpret_cast<const float4*>(g + (size_t)row * 216 + col * 4);
                *reinterpret_cast<float4*>(&lds[row * SPR + col * 4]) = v;
            }
        }
        __syncthreads();

        // ---- compute the 8 joints of this group (chain: parent always < j) ----
        #pragma unroll
        for (int jl = 0; jl < 8; ++jl) {
            const int j  = 8 * gidx + jl;
            const int pj = PAR[j];
            float L[9];
            #pragma unroll
            for (int k = 0; k < 9; ++k) L[k] = lds[t * SPR + jl * 9 + k];

            float rel[3];
            if (j == 0) {
                rel[0] = P[0]; rel[1] = P[1]; rel[2] = P[2];
            } else {
                rel[0] = P[3*j+0] - P[3*pj+0];
                rel[1] = P[3*j+1] - P[3*pj+1];
                rel[2] = P[3*j+2] - P[3*pj+2];
            }
            if (j == 0) {
                #pragma unroll
                for (int k = 0; k < 9; ++k) Rg[0][k] = L[k];
                tg[0][0] = rel[0]; tg[0][1] = rel[1]; tg[0][2] = rel[2];
            } else {
                #pragma unroll
                for (int r = 0; r < 3; ++r) {
                    #pragma unroll
                    for (int c = 0; c < 3; ++c) {
                        Rg[j][3*r+c] = Rg[pj][3*r+0] * L[0+c]
                                     + Rg[pj][3*r+1] * L[3+c]
                                     + Rg[pj][3*r+2] * L[6+c];
                    }
                    tg[j][r] = Rg[pj][3*r+0] * rel[0]
                             + Rg[pj][3*r+1] * rel[1]
                             + Rg[pj][3*r+2] * rel[2]
                             + tg[pj][r];
                }
            }
        }
        __syncthreads();  // done reading rot from LDS

        // ---- oT: stage + coalesced write, two halves of 4 joints each ----
        #pragma unroll
        for (int half = 0; half < 2; ++half) {
            const int j0 = 8 * gidx + 4 * half;
            #pragma unroll
            for (int q = 0; q < 4; ++q) {
                const int j = j0 + q;
                float px = P[3*j], py = P[3*j+1], pz = P[3*j+2];
                #pragma unroll
                for (int r = 0; r < 3; ++r) {
                    float ib = Rg[j][3*r]*px + Rg[j][3*r+1]*py + Rg[j][3*r+2]*pz;
                    float4 v = make_float4(Rg[j][3*r], Rg[j][3*r+1], Rg[j][3*r+2],
                                           tg[j][r] - ib);
                    *reinterpret_cast<float4*>(&lds[t * SOT + (q*4 + r) * 4]) = v;
                }
                *reinterpret_cast<float4*>(&lds[t * SOT + (q*4 + 3) * 4]) =
                    make_float4(0.f, 0.f, 0.f, 1.f);
            }
            __syncthreads();
            {
                float* g = outT + (size_t)b0 * 384 + j0 * 16;
                #pragma unroll
                for (int i = 0; i < 16; ++i) {
                    int f = t + BLK * i;
                    int row = f >> 4, col = f & 15;
                    float4 v = *reinterpret_cast<const float4*>(&lds[row * SOT + col * 4]);
                    *reinterpret_cast<float4*>(g + (size_t)row * 384 + col * 4) = v;
                }
            }
            __syncthreads();
        }

        // ---- oP: stage this group's 8 translations + coalesced write ----
        #pragma unroll
        for (int jl = 0; jl < 8; ++jl) {
            const int j = 8 * gidx + jl;
            lds[t * SOP + jl * 3 + 0] = tg[j][0];
            lds[t * SOP + jl * 3 + 1] = tg[j][1];
            lds[t * SOP + jl * 3 + 2] = tg[j][2];
        }
        __syncthreads();
        {
            float* g = outP + (size_t)b0 * 72 + gidx * 24;
            #pragma unroll
            for (int i = 0; i < 6; ++i) {
                int f = t + BLK * i;
                int row = f / 6, col = f % 6;
                float4 v = *reinterpret_cast<const float4*>(&lds[row * SOP + col * 4]);
                *reinterpret_cast<float4*>(g + (size_t)row * 72 + col * 4) = v;
            }
        }
        // loop-top __syncthreads protects these LDS reads before next stage
    }
}

extern "C" void kernel_launch(void* const* d_in, const int* in_sizes, int n_in,
                              void* d_out, int out_size, void* d_ws, size_t ws_size,
                              hipStream_t stream) {
    const float* rot = (const float*)d_in[0];
    const float* pos = (const float*)d_in[1];
    float* outT = (float*)d_out;
    float* outP = outT + (size_t)NB * NJ * 16;
    dim3 grid(NB / BLK), block(BLK);
    hipLaunchKernelGGL(pose_kernel, grid, block, 0, stream, rot, pos, outT, outP);
}

// Round 6
// 104.779 us; speedup vs baseline: 2.5143x; 1.2916x over previous
//
#include <hip/hip_runtime.h>

namespace {
constexpr int NB  = 131072;
constexpr int NJ  = 24;
constexpr int PAR[NJ] = {0,0,0,0,1,2,3,4,5,6,7,8,9,9,9,12,13,14,16,17,18,19,20,21};
constexpr int BLK = 64;         // one wave per block; batches per block
constexpr int SPR = 76;         // LDS row stride (floats) pos/rot/oP staging (72 data + 4 pad)
constexpr int SOT = 68;         // LDS row stride (floats) oT staging (64 data + 4 pad)
constexpr int LDSW = BLK * SPR; // 4864 floats = 19456 B -> 8 blocks/CU
}

__global__ __launch_bounds__(BLK) void pose_kernel(
    const float* __restrict__ rot,
    const float* __restrict__ pos,
    float* __restrict__ outT,
    float* __restrict__ outP)
{
    __shared__ __align__(16) float lds[LDSW];
    const int t  = threadIdx.x;   // 0..63, lane == batch within block
    const int b0 = blockIdx.x * BLK;

    // ---- stage positions (64 rows x 72 floats) coalesced -> LDS ----
    {
        const float* g = pos + (size_t)b0 * 72;
        #pragma unroll
        for (int i = 0; i < 18; ++i) {
            int f = t + BLK * i;          // float4 index, 1152 total
            int row = f / 18, col = f % 18;
            float4 v = *reinterpret_cast<const float4*>(g + (size_t)row * 72 + col * 4);
            *reinterpret_cast<float4*>(&lds[row * SPR + col * 4]) = v;
        }
    }
    __syncthreads();
    float P[72];
    #pragma unroll
    for (int i = 0; i < 18; ++i) {
        float4 v = *reinterpret_cast<const float4*>(&lds[t * SPR + i * 4]);
        P[4*i+0] = v.x; P[4*i+1] = v.y; P[4*i+2] = v.z; P[4*i+3] = v.w;
    }

    float Rg[NJ][9];
    float tg[NJ][3];

    #pragma unroll
    for (int gidx = 0; gidx < 3; ++gidx) {
        __syncthreads();  // previous LDS contents fully consumed

        // ---- stage rot for joints 8g..8g+7 (72 floats/row) coalesced -> LDS ----
        {
            const float* g = rot + (size_t)b0 * 216 + gidx * 72;
            #pragma unroll
            for (int i = 0; i < 18; ++i) {
                int f = t + BLK * i;
                int row = f / 18, col = f % 18;
                float4 v = *reinterpret_cast<const float4*>(g + (size_t)row * 216 + col * 4);
                *reinterpret_cast<float4*>(&lds[row * SPR + col * 4]) = v;
            }
        }
        __syncthreads();

        // ---- compute the 8 joints of this group (parent always < j) ----
        #pragma unroll
        for (int jl = 0; jl < 8; ++jl) {
            const int j  = 8 * gidx + jl;
            const int pj = PAR[j];
            float L[9];
            #pragma unroll
            for (int k = 0; k < 9; ++k) L[k] = lds[t * SPR + jl * 9 + k];

            float rel[3];
            if (j == 0) {
                rel[0] = P[0]; rel[1] = P[1]; rel[2] = P[2];
            } else {
                rel[0] = P[3*j+0] - P[3*pj+0];
                rel[1] = P[3*j+1] - P[3*pj+1];
                rel[2] = P[3*j+2] - P[3*pj+2];
            }
            if (j == 0) {
                #pragma unroll
                for (int k = 0; k < 9; ++k) Rg[0][k] = L[k];
                tg[0][0] = rel[0]; tg[0][1] = rel[1]; tg[0][2] = rel[2];
            } else {
                #pragma unroll
                for (int r = 0; r < 3; ++r) {
                    #pragma unroll
                    for (int c = 0; c < 3; ++c) {
                        Rg[j][3*r+c] = Rg[pj][3*r+0] * L[0+c]
                                     + Rg[pj][3*r+1] * L[3+c]
                                     + Rg[pj][3*r+2] * L[6+c];
                    }
                    tg[j][r] = Rg[pj][3*r+0] * rel[0]
                             + Rg[pj][3*r+1] * rel[1]
                             + Rg[pj][3*r+2] * rel[2]
                             + tg[pj][r];
                }
            }
        }
        __syncthreads();  // done reading rot from LDS

        // ---- oT: stage + coalesced write, two halves of 4 joints each ----
        #pragma unroll
        for (int half = 0; half < 2; ++half) {
            const int j0 = 8 * gidx + 4 * half;
            #pragma unroll
            for (int q = 0; q < 4; ++q) {
                const int j = j0 + q;
                float px = P[3*j], py = P[3*j+1], pz = P[3*j+2];
                #pragma unroll
                for (int r = 0; r < 3; ++r) {
                    float ib = Rg[j][3*r]*px + Rg[j][3*r+1]*py + Rg[j][3*r+2]*pz;
                    float4 v = make_float4(Rg[j][3*r], Rg[j][3*r+1], Rg[j][3*r+2],
                                           tg[j][r] - ib);
                    *reinterpret_cast<float4*>(&lds[t * SOT + (q*4 + r) * 4]) = v;
                }
                *reinterpret_cast<float4*>(&lds[t * SOT + (q*4 + 3) * 4]) =
                    make_float4(0.f, 0.f, 0.f, 1.f);
            }
            __syncthreads();
            {
                float* g = outT + (size_t)b0 * 384 + j0 * 16;
                #pragma unroll
                for (int i = 0; i < 16; ++i) {
                    int f = t + BLK * i;          // 1024 float4s = 64 rows x 16
                    int row = f >> 4, col = f & 15;
                    float4 v = *reinterpret_cast<const float4*>(&lds[row * SOT + col * 4]);
                    *reinterpret_cast<float4*>(g + (size_t)row * 384 + col * 4) = v;
                }
            }
            __syncthreads();
        }

        // ---- oP: stage this group's 8 translations (24 floats/row) + write ----
        #pragma unroll
        for (int i = 0; i < 6; ++i) {
            float vals[4];
            #pragma unroll
            for (int k = 0; k < 4; ++k) {
                int e = 4*i + k;                  // 0..23, all static
                int j = 8*gidx + e/3, c = e % 3;
                vals[k] = tg[j][c];
            }
            *reinterpret_cast<float4*>(&lds[t * SPR + i * 4]) =
                make_float4(vals[0], vals[1], vals[2], vals[3]);
        }
        __syncthreads();
        {
            float* g = outP + (size_t)b0 * 72 + gidx * 24;
            #pragma unroll
            for (int i = 0; i < 6; ++i) {
                int f = t + BLK * i;              // 384 float4s = 64 rows x 6
                int row = f / 6, col = f % 6;
                float4 v = *reinterpret_cast<const float4*>(&lds[row * SPR + col * 4]);
                *reinterpret_cast<float4*>(g + (size_t)row * 72 + col * 4) = v;
            }
        }
        // loop-top __syncthreads protects these LDS reads before next overwrite
    }
}

extern "C" void kernel_launch(void* const* d_in, const int* in_sizes, int n_in,
                              void* d_out, int out_size, void* d_ws, size_t ws_size,
                              hipStream_t stream) {
    const float* rot = (const float*)d_in[0];
    const float* pos = (const float*)d_in[1];
    float* outT = (float*)d_out;
    float* outP = outT + (size_t)NB * NJ * 16;
    dim3 grid(NB / BLK), block(BLK);
    hipLaunchKernelGGL(pose_kernel, grid, block, 0, stream, rot, pos, outT, outP);
}

// Round 7
// 92.249 us; speedup vs baseline: 2.8558x; 1.1358x over previous
//
#include <hip/hip_runtime.h>

namespace {
constexpr int NB  = 131072;
constexpr int NJ  = 24;
constexpr int PAR[NJ] = {0,0,0,0,1,2,3,4,5,6,7,8,9,9,9,12,13,14,16,17,18,19,20,21};
constexpr int BLK = 64;         // one wave per block; batches per block
constexpr int SPR = 76;         // LDS row stride (floats) pos/rot/oP staging (72 data + 4 pad)
constexpr int SOT = 68;         // LDS row stride (floats) oT staging (64 data + 4 pad)
constexpr int LDSW = BLK * SPR; // 4864 floats = 19456 B -> 8 blocks/CU
}

typedef float f32x4 __attribute__((ext_vector_type(4)));

__global__ __launch_bounds__(BLK) void pose_kernel(
    const float* __restrict__ rot,
    const float* __restrict__ pos,
    float* __restrict__ outT,
    float* __restrict__ outP)
{
    __shared__ __align__(16) float lds[LDSW];
    const int t  = threadIdx.x;   // 0..63, lane == batch within block
    const int b0 = blockIdx.x * BLK;

    // ---- stage positions (64 rows x 72 floats) coalesced -> LDS ----
    {
        const float* g = pos + (size_t)b0 * 72;
        #pragma unroll
        for (int i = 0; i < 18; ++i) {
            int f = t + BLK * i;          // float4 index, 1152 total
            int row = f / 18, col = f % 18;
            float4 v = *reinterpret_cast<const float4*>(g + (size_t)row * 72 + col * 4);
            *reinterpret_cast<float4*>(&lds[row * SPR + col * 4]) = v;
        }
    }
    __syncthreads();
    float P[72];
    #pragma unroll
    for (int i = 0; i < 18; ++i) {
        float4 v = *reinterpret_cast<const float4*>(&lds[t * SPR + i * 4]);
        P[4*i+0] = v.x; P[4*i+1] = v.y; P[4*i+2] = v.z; P[4*i+3] = v.w;
    }

    float Rg[NJ][9];
    float tg[NJ][3];

    #pragma unroll
    for (int gidx = 0; gidx < 3; ++gidx) {
        __syncthreads();  // previous LDS contents fully consumed

        // ---- stage rot for joints 8g..8g+7 (72 floats/row) coalesced -> LDS ----
        {
            const float* g = rot + (size_t)b0 * 216 + gidx * 72;
            #pragma unroll
            for (int i = 0; i < 18; ++i) {
                int f = t + BLK * i;
                int row = f / 18, col = f % 18;
                float4 v = *reinterpret_cast<const float4*>(g + (size_t)row * 216 + col * 4);
                *reinterpret_cast<float4*>(&lds[row * SPR + col * 4]) = v;
            }
        }
        __syncthreads();

        // ---- compute the 8 joints of this group (parent always < j) ----
        // Per joint: 3x ds_read_b128 (bank-balanced) + static extraction,
        // replacing 9 scalar b32 reads (which are 8-way conflicted at SPR=76).
        #pragma unroll
        for (int jl = 0; jl < 8; ++jl) {
            const int j  = 8 * gidx + jl;
            const int pj = PAR[j];
            const int c0 = (9 * jl) >> 2;   // static after unroll
            const int o  = (9 * jl) & 3;    // static after unroll
            float buf[12];
            #pragma unroll
            for (int q = 0; q < 3; ++q) {
                float4 v = *reinterpret_cast<const float4*>(&lds[t * SPR + (c0 + q) * 4]);
                buf[4*q+0] = v.x; buf[4*q+1] = v.y; buf[4*q+2] = v.z; buf[4*q+3] = v.w;
            }
            float L[9];
            #pragma unroll
            for (int k = 0; k < 9; ++k) L[k] = buf[o + k];

            float rel[3];
            if (j == 0) {
                rel[0] = P[0]; rel[1] = P[1]; rel[2] = P[2];
            } else {
                rel[0] = P[3*j+0] - P[3*pj+0];
                rel[1] = P[3*j+1] - P[3*pj+1];
                rel[2] = P[3*j+2] - P[3*pj+2];
            }
            if (j == 0) {
                #pragma unroll
                for (int k = 0; k < 9; ++k) Rg[0][k] = L[k];
                tg[0][0] = rel[0]; tg[0][1] = rel[1]; tg[0][2] = rel[2];
            } else {
                #pragma unroll
                for (int r = 0; r < 3; ++r) {
                    #pragma unroll
                    for (int c = 0; c < 3; ++c) {
                        Rg[j][3*r+c] = Rg[pj][3*r+0] * L[0+c]
                                     + Rg[pj][3*r+1] * L[3+c]
                                     + Rg[pj][3*r+2] * L[6+c];
                    }
                    tg[j][r] = Rg[pj][3*r+0] * rel[0]
                             + Rg[pj][3*r+1] * rel[1]
                             + Rg[pj][3*r+2] * rel[2]
                             + tg[pj][r];
                }
            }
        }
        __syncthreads();  // done reading rot from LDS; buffer reused for oT

        // ---- oT: stage + coalesced nontemporal write, two halves of 4 joints ----
        #pragma unroll
        for (int half = 0; half < 2; ++half) {
            const int j0 = 8 * gidx + 4 * half;
            #pragma unroll
            for (int q = 0; q < 4; ++q) {
                const int j = j0 + q;
                float px = P[3*j], py = P[3*j+1], pz = P[3*j+2];
                #pragma unroll
                for (int r = 0; r < 3; ++r) {
                    float ib = Rg[j][3*r]*px + Rg[j][3*r+1]*py + Rg[j][3*r+2]*pz;
                    float4 v = make_float4(Rg[j][3*r], Rg[j][3*r+1], Rg[j][3*r+2],
                                           tg[j][r] - ib);
                    *reinterpret_cast<float4*>(&lds[t * SOT + (q*4 + r) * 4]) = v;
                }
                *reinterpret_cast<float4*>(&lds[t * SOT + (q*4 + 3) * 4]) =
                    make_float4(0.f, 0.f, 0.f, 1.f);
            }
            __syncthreads();
            {
                float* g = outT + (size_t)b0 * 384 + j0 * 16;
                #pragma unroll
                for (int i = 0; i < 16; ++i) {
                    int f = t + BLK * i;          // 1024 float4s = 64 rows x 16
                    int row = f >> 4, col = f & 15;
                    f32x4 v = *reinterpret_cast<const f32x4*>(&lds[row * SOT + col * 4]);
                    __builtin_nontemporal_store(
                        v, reinterpret_cast<f32x4*>(g + (size_t)row * 384 + col * 4));
                }
            }
            __syncthreads();
        }
    }

    // ---- oP: all 24 joints staged once, full-line (288 B/row) nt write ----
    // (trailing __syncthreads of the last oT half protects LDS reuse)
    #pragma unroll
    for (int i = 0; i < 18; ++i) {
        float vals[4];
        #pragma unroll
        for (int k = 0; k < 4; ++k) {
            int e = 4*i + k;                  // 0..71, all static
            int j = e / 3, c = e % 3;
            vals[k] = tg[j][c];
        }
        *reinterpret_cast<float4*>(&lds[t * SPR + i * 4]) =
            make_float4(vals[0], vals[1], vals[2], vals[3]);
    }
    __syncthreads();
    {
        float* g = outP + (size_t)b0 * 72;
        #pragma unroll
        for (int i = 0; i < 18; ++i) {
            int f = t + BLK * i;              // 1152 float4s = 64 rows x 18
            int row = f / 18, col = f % 18;
            f32x4 v = *reinterpret_cast<const f32x4*>(&lds[row * SPR + col * 4]);
            __builtin_nontemporal_store(
                v, reinterpret_cast<f32x4*>(g + (size_t)row * 72 + col * 4));
        }
    }
}

extern "C" void kernel_launch(void* const* d_in, const int* in_sizes, int n_in,
                              void* d_out, int out_size, void* d_ws, size_t ws_size,
                              hipStream_t stream) {
    const float* rot = (const float*)d_in[0];
    const float* pos = (const float*)d_in[1];
    float* outT = (float*)d_out;
    float* outP = outT + (size_t)NB * NJ * 16;
    dim3 grid(NB / BLK), block(BLK);
    hipLaunchKernelGGL(pose_kernel, grid, block, 0, stream, rot, pos, outT, outP);
}

// Round 8
// 66.666 us; speedup vs baseline: 3.9517x; 1.3837x over previous
//
#include <hip/hip_runtime.h>

namespace {
constexpr int NB  = 131072;
constexpr int NJ  = 24;
constexpr int PAR[NJ] = {0,0,0,0,1,2,3,4,5,6,7,8,9,9,9,12,13,14,16,17,18,19,20,21};
constexpr int BLK = 64;         // one wave per block; batches per block
constexpr int SOT = 68;         // LDS row stride (floats) oT staging (64 data + 4 pad)
constexpr int SPO = 76;         // LDS row stride (floats) oP staging (72 data + 4 pad)
constexpr int LDSF = BLK * SPO; // 19456 B -> 8 blocks/CU
}

typedef float f32x4 __attribute__((ext_vector_type(4)));

// Single-wave blocks: NO __syncthreads anywhere. Intra-wave cross-lane LDS
// communication is ordered by lgkmcnt (compiler-inserted) + per-wave FIFO
// LDS processing. Removing the barriers removes the vmcnt(0) store-drains
// that serialized every phase against HBM round-trip latency.
__global__ __launch_bounds__(BLK) void pose_kernel(
    const float* __restrict__ rot,
    const float* __restrict__ pos,
    float* __restrict__ outT,
    float* __restrict__ outP)
{
    __shared__ __align__(16) float lds[LDSF];
    const int t  = threadIdx.x;   // 0..63, lane == batch within block
    const int b0 = blockIdx.x * BLK;

    const float* prow = pos + (size_t)(b0 + t) * 72;   // this thread's pos row
    const float* rrow = rot + (size_t)(b0 + t) * 216;  // this thread's rot row

    float Rg[NJ][9];
    float tg[NJ][3];
    float carry1[9];   // P of joints 5,6,7   (needed by group 1)
    float carry2[6];   // P of joints 13,14   (needed by group 2)

    #pragma unroll
    for (int g = 0; g < 3; ++g) {
        // ---- group-local positions: joints 8g..8g+7 = floats [24g, 24g+24) ----
        float Pg[24];
        #pragma unroll
        for (int i = 0; i < 6; ++i) {
            f32x4 v = *reinterpret_cast<const f32x4*>(prow + 24 * g + 4 * i);
            Pg[4*i+0] = v.x; Pg[4*i+1] = v.y; Pg[4*i+2] = v.z; Pg[4*i+3] = v.w;
        }

        #pragma unroll
        for (int q = 0; q < 2; ++q) {           // quad = 4 joints
            // ---- direct rot loads: floats [72g+36q, +36) of this row ----
            float buf[36];
            #pragma unroll
            for (int i = 0; i < 9; ++i) {
                f32x4 v = *reinterpret_cast<const f32x4*>(rrow + 72 * g + 36 * q + 4 * i);
                buf[4*i+0] = v.x; buf[4*i+1] = v.y; buf[4*i+2] = v.z; buf[4*i+3] = v.w;
            }

            // ---- compute 4 joints (parent always < j; all indices static) ----
            #pragma unroll
            for (int l = 0; l < 4; ++l) {
                const int j  = 8 * g + 4 * q + l;
                const int pj = PAR[j];
                float L[9];
                #pragma unroll
                for (int k = 0; k < 9; ++k) L[k] = buf[9 * (4 * q + l) - 36 * q + k];

                if (j == 0) {
                    #pragma unroll
                    for (int k = 0; k < 9; ++k) Rg[0][k] = L[k];
                    tg[0][0] = Pg[0]; tg[0][1] = Pg[1]; tg[0][2] = Pg[2];
                } else {
                    float pxp, pyp, pzp;
                    if (pj >= 8 * g) {                 // parent in this group
                        const int lp = 3 * pj - 24 * g;
                        pxp = Pg[lp]; pyp = Pg[lp+1]; pzp = Pg[lp+2];
                    } else if (g == 1) {               // parent in {5,6,7}
                        const int ci = 3 * (pj - 5);
                        pxp = carry1[ci]; pyp = carry1[ci+1]; pzp = carry1[ci+2];
                    } else {                           // g==2, parent in {13,14}
                        const int ci = 3 * (pj - 13);
                        pxp = carry2[ci]; pyp = carry2[ci+1]; pzp = carry2[ci+2];
                    }
                    const int lj = 3 * j - 24 * g;
                    float rel[3] = { Pg[lj] - pxp, Pg[lj+1] - pyp, Pg[lj+2] - pzp };
                    #pragma unroll
                    for (int r = 0; r < 3; ++r) {
                        #pragma unroll
                        for (int c = 0; c < 3; ++c) {
                            Rg[j][3*r+c] = Rg[pj][3*r+0] * L[0+c]
                                         + Rg[pj][3*r+1] * L[3+c]
                                         + Rg[pj][3*r+2] * L[6+c];
                        }
                        tg[j][r] = Rg[pj][3*r+0] * rel[0]
                                 + Rg[pj][3*r+1] * rel[1]
                                 + Rg[pj][3*r+2] * rel[2]
                                 + tg[pj][r];
                    }
                }
            }

            // ---- oT: stage this quad (64 floats/row) then coalesced nt write ----
            #pragma unroll
            for (int l = 0; l < 4; ++l) {
                const int j  = 8 * g + 4 * q + l;
                const int lj = 3 * j - 24 * g;
                float px = Pg[lj], py = Pg[lj+1], pz = Pg[lj+2];
                #pragma unroll
                for (int r = 0; r < 3; ++r) {
                    float ib = Rg[j][3*r]*px + Rg[j][3*r+1]*py + Rg[j][3*r+2]*pz;
                    *reinterpret_cast<f32x4*>(&lds[t * SOT + (l*4 + r) * 4]) =
                        f32x4{Rg[j][3*r], Rg[j][3*r+1], Rg[j][3*r+2], tg[j][r] - ib};
                }
                *reinterpret_cast<f32x4*>(&lds[t * SOT + (l*4 + 3) * 4]) =
                    f32x4{0.f, 0.f, 0.f, 1.f};
            }
            {
                float* gp = outT + (size_t)b0 * 384 + (8 * g + 4 * q) * 16;
                #pragma unroll
                for (int i = 0; i < 16; ++i) {
                    int f = t + BLK * i;          // 1024 f4 = 64 rows x 16
                    int row = f >> 4, col = f & 15;
                    f32x4 v = *reinterpret_cast<const f32x4*>(&lds[row * SOT + col * 4]);
                    __builtin_nontemporal_store(
                        v, reinterpret_cast<f32x4*>(gp + (size_t)row * 384 + col * 4));
                }
            }
        }

        // ---- save cross-group parent positions (all static) ----
        if (g == 0) {
            #pragma unroll
            for (int k = 0; k < 9; ++k) carry1[k] = Pg[15 + k];   // joints 5,6,7
        } else if (g == 1) {
            #pragma unroll
            for (int k = 0; k < 6; ++k) carry2[k] = Pg[15 + k];   // joints 13,14
        }
    }

    // ---- oP: stage all 24 translations (72 floats/row), coalesced nt write ----
    #pragma unroll
    for (int i = 0; i < 18; ++i) {
        float vals[4];
        #pragma unroll
        for (int k = 0; k < 4; ++k) {
            int e = 4*i + k;                  // 0..71, static
            vals[k] = tg[e / 3][e % 3];
        }
        *reinterpret_cast<f32x4*>(&lds[t * SPO + i * 4]) =
            f32x4{vals[0], vals[1], vals[2], vals[3]};
    }
    {
        float* gp = outP + (size_t)b0 * 72;
        #pragma unroll
        for (int i = 0; i < 18; ++i) {
            int f = t + BLK * i;              // 1152 f4 = 64 rows x 18
            int row = f / 18, col = f % 18;
            f32x4 v = *reinterpret_cast<const f32x4*>(&lds[row * SPO + col * 4]);
            __builtin_nontemporal_store(
                v, reinterpret_cast<f32x4*>(gp + (size_t)row * 72 + col * 4));
        }
    }
}

extern "C" void kernel_launch(void* const* d_in, const int* in_sizes, int n_in,
                              void* d_out, int out_size, void* d_ws, size_t ws_size,
                              hipStream_t stream) {
    const float* rot = (const float*)d_in[0];
    const float* pos = (const float*)d_in[1];
    float* outT = (float*)d_out;
    float* outP = outT + (size_t)NB * NJ * 16;
    dim3 grid(NB / BLK), block(BLK);
    hipLaunchKernelGGL(pose_kernel, grid, block, 0, stream, rot, pos, outT, outP);
}